// Round 3
// baseline (32.389 us; speedup 1.0000x reference)
//
#include <hip/hip_runtime.h>

#define IMG   512
#define NCLS  256
#define DIM   1024
#define HPW   32

typedef short bf16x8 __attribute__((ext_vector_type(8)));
typedef float f32x4  __attribute__((ext_vector_type(4)));

__device__ inline ushort f32_to_bf16_rne(float v) {
    unsigned u = __float_as_uint(v);
    unsigned r = u + 0x7fffu + ((u >> 16) & 1u);
    return (ushort)(r >> 16);
}

// ---------------- prep: per-patch histograms (bf16 A matrix) + table transpose ----
// blocks [0, hb)          : histogram, 4 patches per block  (hb = tokens/4)
// blocks [hb, hb+64)      : transpose table -> Tt bf16 [1024][256]
__global__ __launch_bounds__(256)
void prep_kernel(const int* __restrict__ smap, const float* __restrict__ table,
                 ushort* __restrict__ A, ushort* __restrict__ Tt, int hb)
{
    __shared__ unsigned cnt[4 * NCLS];       // 4 KB (hist path)
    __shared__ ushort   tile[64][66];        // 8.25 KB (transpose path)
    const int t = threadIdx.x;

    if ((int)blockIdx.x < hb) {
        // ---- histogram of 4 patches (1024 px), one wave per patch ----
        #pragma unroll
        for (int i = t; i < 4 * NCLS; i += 256) cnt[i] = 0u;
        __syncthreads();

        const int pgrp = t >> 6;             // patch within block
        const int lane = t & 63;
        const int p  = blockIdx.x * 4 + pgrp;            // patch id == token id
        const int b  = p >> 10, ph = (p >> 5) & 31, pw = p & 31;
        const int* base = smap + ((size_t)b * IMG + (size_t)ph * 16) * IMG + (size_t)pw * 16;
        const int row = lane >> 2, col = (lane & 3) * 4;
        const int4 q = *reinterpret_cast<const int4*>(base + (size_t)row * IMG + col);
        unsigned* hp = &cnt[pgrp * NCLS];
        atomicAdd(&hp[min(max(q.x, 0), NCLS - 1)], 1u);
        atomicAdd(&hp[min(max(q.y, 0), NCLS - 1)], 1u);
        atomicAdd(&hp[min(max(q.z, 0), NCLS - 1)], 1u);
        atomicAdd(&hp[min(max(q.w, 0), NCLS - 1)], 1u);
        __syncthreads();

        // counts -> bf16(count/256) (exact, <=8 significant bits); 4 bins/thread
        const int i0 = t * 4;
        ushort4 o;
        o.x = (ushort)(__float_as_uint((float)cnt[i0 + 0] * (1.0f / 256.0f)) >> 16);
        o.y = (ushort)(__float_as_uint((float)cnt[i0 + 1] * (1.0f / 256.0f)) >> 16);
        o.z = (ushort)(__float_as_uint((float)cnt[i0 + 2] * (1.0f / 256.0f)) >> 16);
        o.w = (ushort)(__float_as_uint((float)cnt[i0 + 3] * (1.0f / 256.0f)) >> 16);
        *reinterpret_cast<ushort4*>(&A[(size_t)blockIdx.x * 1024 + i0]) = o;
    } else {
        // ---- transpose 64x64 tile of table to bf16 ----
        const int bid2 = blockIdx.x - hb;
        const int c0 = (bid2 & 3) * 64;
        const int d0 = (bid2 >> 2) * 64;
        #pragma unroll
        for (int it = 0; it < 16; ++it) {
            const int idx = it * 256 + t;
            const int cl = idx >> 6, dl = idx & 63;      // coalesced along dims
            tile[dl][cl] = f32_to_bf16_rne(table[(size_t)(c0 + cl) * DIM + d0 + dl]);
        }
        __syncthreads();
        #pragma unroll
        for (int it = 0; it < 16; ++it) {
            const int idx = it * 256 + t;
            const int dl = idx >> 6, cl = idx & 63;      // coalesced along classes
            Tt[(size_t)(d0 + dl) * NCLS + c0 + cl] = tile[dl][cl];
        }
    }
}

// ---------------- main: MFMA GEMM (16 tok x 1024 dim x 256 cls) + pos + LN --------
__global__ __launch_bounds__(1024)
void gemm_ln(const ushort* __restrict__ A, const ushort* __restrict__ Tt,
             const float* __restrict__ gamma, const float* __restrict__ beta,
             float* __restrict__ out)
{
    __shared__ float red[16][4][4][2];       // [wave][g][i][{s,s2}]

    const int t    = threadIdx.x;
    const int lane = t & 63;
    const int w    = t >> 6;                 // 16 waves; wave owns dims [w*64, w*64+64)
    const int c    = lane & 15;
    const int g    = lane >> 4;

    const int m   = blockIdx.x;              // M-tile: tokens m*16 .. m*16+16
    const int ph  = (m >> 1) & 31;
    const int pw0 = (m & 1) * 16;

    f32x4 acc[4];
    #pragma unroll
    for (int i = 0; i < 4; ++i) acc[i] = (f32x4){0.f, 0.f, 0.f, 0.f};

    const ushort* abase = A  + (size_t)(m * 16 + c) * NCLS + g * 8;
    const ushort* bbase = Tt + (size_t)(w * 64 + c) * NCLS + g * 8;

    #pragma unroll 2
    for (int ks = 0; ks < 8; ++ks) {
        const bf16x8 a = *reinterpret_cast<const bf16x8*>(abase + ks * 32);
        #pragma unroll
        for (int tt = 0; tt < 4; ++tt) {
            const bf16x8 bf = *reinterpret_cast<const bf16x8*>(bbase + (size_t)tt * 16 * NCLS + ks * 32);
            acc[tt] = __builtin_amdgcn_mfma_f32_16x16x32_bf16(a, bf, acc[tt], 0, 0, 0);
        }
    }

    // ---- pos-embed + LN partials.  D: row r=g*4+i (token), col c (dim offset) ----
    const int quad   = w >> 2;               // d>>8, constant per wave
    const int cosSel = quad & 1;
    float ls[4]  = {0.f, 0.f, 0.f, 0.f};
    float ls2[4] = {0.f, 0.f, 0.f, 0.f};

    #pragma unroll
    for (int tt = 0; tt < 4; ++tt) {
        const int d = w * 64 + tt * 16 + c;
        const float omega = exp2f((float)(d & 255) * (-13.287712379549449f / 256.0f));
        if (quad < 2) {                      // h-embed: same for all 4 tokens
            float sv, cv;
            __sincosf((float)ph * omega, &sv, &cv);
            const float v = cosSel ? cv : sv;
            #pragma unroll
            for (int i = 0; i < 4; ++i) acc[tt][i] += v;
        } else {                             // w-embed: pw = pw0 + r
            #pragma unroll
            for (int i = 0; i < 4; ++i) {
                float sv, cv;
                __sincosf((float)(pw0 + g * 4 + i) * omega, &sv, &cv);
                acc[tt][i] += cosSel ? cv : sv;
            }
        }
        #pragma unroll
        for (int i = 0; i < 4; ++i) {
            ls[i]  += acc[tt][i];
            ls2[i] += acc[tt][i] * acc[tt][i];
        }
    }

    #pragma unroll
    for (int off = 1; off < 16; off <<= 1) {
        #pragma unroll
        for (int i = 0; i < 4; ++i) {
            ls[i]  += __shfl_xor(ls[i],  off, 64);
            ls2[i] += __shfl_xor(ls2[i], off, 64);
        }
    }
    if (c == 0) {
        #pragma unroll
        for (int i = 0; i < 4; ++i) { red[w][g][i][0] = ls[i]; red[w][g][i][1] = ls2[i]; }
    }
    __syncthreads();

    float mu[4], rs[4];
    #pragma unroll
    for (int i = 0; i < 4; ++i) {
        float S = 0.f, S2 = 0.f;
        #pragma unroll
        for (int ww = 0; ww < 16; ++ww) { S += red[ww][g][i][0]; S2 += red[ww][g][i][1]; }
        mu[i] = S * (1.0f / DIM);
        rs[i] = rsqrtf(S2 * (1.0f / DIM) - mu[i] * mu[i] + 1e-5f);
    }

    #pragma unroll
    for (int tt = 0; tt < 4; ++tt) {
        const int d = w * 64 + tt * 16 + c;
        const float gv = gamma[d], bv = beta[d];
        #pragma unroll
        for (int i = 0; i < 4; ++i) {
            const int r = g * 4 + i;
            out[(size_t)(m * 16 + r) * DIM + d] = (acc[tt][i] - mu[i]) * rs[i] * gv + bv;
        }
    }
}

extern "C" void kernel_launch(void* const* d_in, const int* in_sizes, int n_in,
                              void* d_out, int out_size, void* d_ws, size_t ws_size,
                              hipStream_t stream) {
    const int*   smap  = (const int*)d_in[0];
    const float* table = (const float*)d_in[1];
    const float* gamma = (const float*)d_in[2];
    const float* beta  = (const float*)d_in[3];
    float*       out   = (float*)d_out;

    const int batches = in_sizes[0] / (IMG * IMG);       // = 2
    const int tokens  = batches * HPW * HPW;             // 2048
    const int hb      = tokens / 4;                      // histogram blocks

    ushort* A  = (ushort*)d_ws;                          // [tokens][256] bf16 (1 MB)
    ushort* Tt = (ushort*)d_ws + (size_t)tokens * NCLS;  // [1024][256] bf16 (512 KB)

    prep_kernel<<<hb + 64, 256, 0, stream>>>(smap, table, A, Tt, hb);
    gemm_ln<<<tokens / 16, 1024, 0, stream>>>(A, Tt, gamma, beta, out);
}

// Round 4
// 25.750 us; speedup vs baseline: 1.2578x; 1.2578x over previous
//
#include <hip/hip_runtime.h>
#include <hip/hip_bf16.h>

#define IMG   512
#define NCLS  256
#define DIM   1024
#define HPW   32
#define TPB   8            // tokens (patches) per block
#define NT    1024         // threads per block = 16 waves; wave owns 64 dims

typedef short bf16x8 __attribute__((ext_vector_type(8)));
typedef float f32x4  __attribute__((ext_vector_type(4)));

__global__ __launch_bounds__(NT)
void fused_semtok(const int* __restrict__ smap, const float* __restrict__ table,
                  const float* __restrict__ gamma, const float* __restrict__ beta,
                  float* __restrict__ out)
{
    __shared__ unsigned cnt[TPB * NCLS];      // 8 KB histogram
    __shared__ ushort   cntb[16][NCLS + 8];   // bf16 counts/256; rows 8..15 stay zero
    __shared__ float    red[16][2][4][2];     // [wave][g][i][{s,s2}]

    const int t    = threadIdx.x;
    const int lane = t & 63;
    const int w    = t >> 6;                  // wave id; dims [w*64, w*64+64)
    const int c    = lane & 15;               // MFMA row (token) for A, col-dim for B/D
    const int g    = lane >> 4;               // MFMA k-group / D-row group

    const int tok0 = blockIdx.x * TPB;        // 8 consecutive tokens, same patch-row
    const int b    = tok0 >> 10;
    const int ph   = (tok0 >> 5) & 31;
    const int pw0  = tok0 & 31;

    // ---- phase 0: zero LDS ----
    for (int i = t; i < TPB * NCLS; i += NT) cnt[i] = 0u;
    for (int i = t; i < 16 * (NCLS + 8); i += NT) (&cntb[0][0])[i] = 0;
    __syncthreads();

    // ---- phase 1: histogram (8 patches = 16 rows x 128 cols, int2 per thread) ----
    {
        const int p   = t * 2;
        const int row = p >> 7;               // 0..15
        const int col = p & 127;
        const int2 q = *reinterpret_cast<const int2*>(
            smap + ((size_t)b * IMG + (size_t)ph * 16 + row) * IMG + (size_t)pw0 * 16 + col);
        unsigned* hp = &cnt[(col >> 4) * NCLS];
        atomicAdd(&hp[min(max(q.x, 0), NCLS - 1)], 1u);
        atomicAdd(&hp[min(max(q.y, 0), NCLS - 1)], 1u);
    }
    __syncthreads();

    // ---- phase 2: counts -> bf16(count/256) (exact: <=8 significant bits) ----
    for (int i = t; i < TPB * NCLS; i += NT) {
        const float f = (float)cnt[i] * (1.0f / 256.0f);
        cntb[i >> 8][i & 255] = (ushort)(__float_as_uint(f) >> 16);  // exact, low bits 0
    }
    __syncthreads();

    // ---- phase 3: MFMA GEMM: D[16 tok x 16 dim] per tile, B from f32 table ----
    f32x4 acc[4];
    #pragma unroll
    for (int i = 0; i < 4; ++i) acc[i] = (f32x4){0.f, 0.f, 0.f, 0.f};

    #pragma unroll
    for (int ks = 0; ks < 8; ++ks) {
        const bf16x8 a = *reinterpret_cast<const bf16x8*>(&cntb[c][g * 8 + ks * 32]);
        #pragma unroll
        for (int tt = 0; tt < 4; ++tt) {
            const int d = w * 64 + tt * 16 + c;
            const float* tb = table + (size_t)(ks * 32 + g * 8) * DIM + d;
            bf16x8 bf;
            #pragma unroll
            for (int j = 0; j < 8; ++j) {
                union { __hip_bfloat16 h; ushort u; } cv;
                cv.h = __float2bfloat16(tb[(size_t)j * DIM]);   // RNE, packs to cvt_pk
                bf[j] = (short)cv.u;
            }
            acc[tt] = __builtin_amdgcn_mfma_f32_16x16x32_bf16(a, bf, acc[tt], 0, 0, 0);
        }
    }

    // ---- phase 4: sincos pos-embed + LN partials ----
    // D layout: row r = g*4+i (token tok0+r, valid r<8), col c; dim d = w*64+tt*16+c
    const int quad   = w >> 2;                // d>>8, constant per wave
    const int cosSel = quad & 1;
    float ls[4]  = {0.f, 0.f, 0.f, 0.f};
    float ls2[4] = {0.f, 0.f, 0.f, 0.f};

    #pragma unroll
    for (int tt = 0; tt < 4; ++tt) {
        const int d = w * 64 + tt * 16 + c;
        const float omega = exp2f((float)(d & 255) * (-13.287712379549449f / 256.0f));
        if (quad < 2) {                       // h-embed: same for all rows
            float sv, cv;
            __sincosf((float)ph * omega, &sv, &cv);
            const float v = cosSel ? cv : sv;
            #pragma unroll
            for (int i = 0; i < 4; ++i) acc[tt][i] += v;
        } else {                              // w-embed: pw = pw0 + r
            #pragma unroll
            for (int i = 0; i < 4; ++i) {
                float sv, cv;
                __sincosf((float)(pw0 + g * 4 + i) * omega, &sv, &cv);
                acc[tt][i] += cosSel ? cv : sv;
            }
        }
        #pragma unroll
        for (int i = 0; i < 4; ++i) {
            ls[i]  += acc[tt][i];
            ls2[i] += acc[tt][i] * acc[tt][i];
        }
    }

    #pragma unroll
    for (int off = 1; off < 16; off <<= 1) {
        #pragma unroll
        for (int i = 0; i < 4; ++i) {
            ls[i]  += __shfl_xor(ls[i],  off, 64);
            ls2[i] += __shfl_xor(ls2[i], off, 64);
        }
    }
    if (c == 0 && g < 2) {
        #pragma unroll
        for (int i = 0; i < 4; ++i) { red[w][g][i][0] = ls[i]; red[w][g][i][1] = ls2[i]; }
    }
    __syncthreads();

    // ---- phase 5: finalize LN, store (rows r = g*4+i, g<2 only) ----
    if (g < 2) {
        float mu[4], rs[4];
        #pragma unroll
        for (int i = 0; i < 4; ++i) {
            float S = 0.f, S2 = 0.f;
            #pragma unroll
            for (int ww = 0; ww < 16; ++ww) { S += red[ww][g][i][0]; S2 += red[ww][g][i][1]; }
            mu[i] = S * (1.0f / DIM);
            rs[i] = rsqrtf(S2 * (1.0f / DIM) - mu[i] * mu[i] + 1e-5f);
        }
        #pragma unroll
        for (int tt = 0; tt < 4; ++tt) {
            const int d  = w * 64 + tt * 16 + c;
            const float gv = gamma[d], bv = beta[d];
            #pragma unroll
            for (int i = 0; i < 4; ++i) {
                const int r = g * 4 + i;
                out[(size_t)(tok0 + r) * DIM + d] = (acc[tt][i] - mu[i]) * rs[i] * gv + bv;
            }
        }
    }
}

extern "C" void kernel_launch(void* const* d_in, const int* in_sizes, int n_in,
                              void* d_out, int out_size, void* d_ws, size_t ws_size,
                              hipStream_t stream) {
    const int*   smap  = (const int*)d_in[0];
    const float* table = (const float*)d_in[1];
    const float* gamma = (const float*)d_in[2];
    const float* beta  = (const float*)d_in[3];
    float*       out   = (float*)d_out;

    const int batches = in_sizes[0] / (IMG * IMG);   // = 2
    const int tokens  = batches * HPW * HPW;         // 2048
    fused_semtok<<<tokens / TPB, NT, 0, stream>>>(smap, table, gamma, beta, out);
}